// Round 17
// baseline (283.687 us; speedup 1.0000x reference)
//
#include <hip/hip_runtime.h>
#include <hip/hip_bf16.h>

// Problem constants
#define V_   16000
#define D_   1024
#define H_   1024
#define E_   8
#define C_   16
#define B_   64
#define S_   512
#define GH_  256
#define NPAIR 128   // B_ * K(=2)

typedef short  bf16x8 __attribute__((ext_vector_type(8)));
typedef ushort u16x8  __attribute__((ext_vector_type(8)));
typedef float  f32x4  __attribute__((ext_vector_type(4)));

static __device__ __forceinline__ ushort f2bf(float f) {
  union { float f; unsigned u; } un; un.f = f;
  unsigned u = un.u;
  return (ushort)((u + 0x7FFFu + ((u >> 16) & 1u)) >> 16);  // RNE
}

static __device__ __forceinline__ unsigned pk2(float lo, float hi) {
  __hip_bfloat162 h = __float22bfloat162_rn(make_float2(lo, hi));  // v_cvt_pk_bf16_f32
  unsigned r; __builtin_memcpy(&r, &h, sizeof(r)); return r;
}

// ---------------------------------------------------------------------------
// Kernel 0 (fused prep):
//  blocks [0,2048): repack exp_w1 (E,D,H) f32 -> w1t bf16 in MFMA-fragment order:
//   ushort offset = ((e*32 + kk)*64 + f)*512 + lane*8, element j holds
//   A[h = f*16 + (lane&15)][k = kk*32 + (lane>>4)*8 + j]
//  blocks [2048,2560): partial pooling partial[b][sb][d]
__global__ void prep_kernel(const float* __restrict__ w1, ushort* __restrict__ w1t,
                            const int* __restrict__ x, const float* __restrict__ emb,
                            float* __restrict__ partial) {
  __shared__ float tile[64][65];
  const int id = blockIdx.x;
  if (id < 2048) {
    const int e = id >> 8, rem = id & 255;
    const int dtile = rem & 15, htile = rem >> 4;
    const int d0 = dtile * 64, h0 = htile * 64;
    const float* src = w1 + (size_t)e * D_ * H_;
    for (int i = threadIdx.x; i < 64 * 64; i += 256) {
      int r = i >> 6, c = i & 63;                 // r: d-local (k), c: h-local
      tile[r][c] = src[(size_t)(d0 + r) * H_ + h0 + c];
    }
    __syncthreads();
    for (int i = threadIdx.x; i < 512; i += 256) {
      int chunk = i >> 6, lane = i & 63;
      int kkl = chunk >> 2, htl = chunk & 3;
      int l15 = lane & 15, l16 = lane >> 4;
      u16x8 v;
      #pragma unroll
      for (int j = 0; j < 8; ++j)
        v[j] = f2bf(tile[kkl * 32 + l16 * 8 + j][htl * 16 + l15]);
      size_t off = ((size_t)((e * 32 + dtile * 2 + kkl) * 64 + htile * 4 + htl)) * 512 + lane * 8;
      *reinterpret_cast<u16x8*>(w1t + off) = v;
    }
  } else {
    const int pid = id - 2048;
    const int b = pid >> 3, sb = pid & 7, t = threadIdx.x;
    const int* xr = x + b * S_ + sb * 64;
    float4 acc = make_float4(0.f, 0.f, 0.f, 0.f);
    #pragma unroll 4
    for (int s = 0; s < 64; ++s) {
      const float4* row = reinterpret_cast<const float4*>(emb + (size_t)xr[s] * D_);
      float4 v = row[t];
      acc.x += v.x; acc.y += v.y; acc.z += v.z; acc.w += v.w;
    }
    reinterpret_cast<float4*>(partial + ((size_t)b * 8 + sb) * D_)[t] = acc;
  }
}

// ---------------------------------------------------------------------------
// Kernel 1: reduce partials + gating MLP + top-2 + renormalize (all f32)
__global__ void gate_kernel(const float* __restrict__ partial,
                            const float* __restrict__ gw1, const float* __restrict__ gb1,
                            const float* __restrict__ gw2, const float* __restrict__ gb2,
                            int* __restrict__ ridx, float* __restrict__ rwgt) {
  const int b = blockIdx.x, j = threadIdx.x;
  __shared__ float pl[D_];
  __shared__ float hid[GH_];
  __shared__ float logits[E_];
  for (int d = j; d < D_; d += 256) {
    float s = 0.f;
    #pragma unroll
    for (int sb = 0; sb < 8; ++sb) s += partial[((size_t)b * 8 + sb) * D_ + d];
    pl[d] = s * (1.f / (float)S_);
  }
  __syncthreads();
  float acc = gb1[j];
  for (int d = 0; d < D_; ++d) acc += pl[d] * gw1[d * GH_ + j];
  hid[j] = fmaxf(acc, 0.f);
  __syncthreads();
  if (j < E_) {
    float l = gb2[j];
    for (int i = 0; i < GH_; ++i) l += hid[i] * gw2[i * E_ + j];
    logits[j] = l;
  }
  __syncthreads();
  if (j == 0) {
    int i0 = 0; float v0 = logits[0];
    for (int i = 1; i < E_; ++i) if (logits[i] > v0) { v0 = logits[i]; i0 = i; }
    int i1 = -1; float v1 = -3.0e38f;
    for (int i = 0; i < E_; ++i) {
      if (i == i0) continue;
      if (logits[i] > v1) { v1 = logits[i]; i1 = i; }
    }
    float r1 = expf(v1 - v0);
    float norm = 1.f + r1;
    ridx[b * 2 + 0] = i0;         ridx[b * 2 + 1] = i1;
    rwgt[b * 2 + 0] = 1.f / norm; rwgt[b * 2 + 1] = r1 / norm;
  }
}

// ---------------------------------------------------------------------------
// Kernel 2: stable counting-rank sort of pairs by expert id. 1 block, 128 thr.
__global__ void sort_pairs_kernel(const int* __restrict__ ridx, int* __restrict__ order) {
  __shared__ int se[NPAIR];
  const int t = threadIdx.x;
  se[t] = ridx[t];
  __syncthreads();
  const int e = se[t];
  int rank = 0;
  for (int j = 0; j < NPAIR; ++j) {
    const int ej = se[j];
    rank += (ej < e || (ej == e && j < t)) ? 1 : 0;
  }
  order[rank] = t;
}

// ---------------------------------------------------------------------------
// Kernel 3: token-stationary gathered GEMM + bias + ReLU + sum over s.
//   EXACT round-12 kernel (best: 256.9 us) + TWO de-lockstep edits:
//   (1) ks-order stagger by wave parity: odd waves do ks=1 before ks=0, so
//       at any instant ~half the waves are in the LDS phase while half are
//       in the L2/MFMA phase -> LDS, L2, and MFMA pipes overlap instead of
//       convoying (the barrier re-syncs phases every interval otherwise).
//   (2) s_setprio(1) around the MFMA cluster (pays only with role-diverse
//       waves, which (1) creates).
//   Block owns 64 tokens x ALL H=1024, K=1024 (gather-once). Token tile
//   (64x1024 bf16, swizzled) in LDS (128 KiB), slab written once, gather 2
//   slabs ahead. 16 waves (wave 64h x 64s, acc[4][4]); 4 waves/SIMD.
// grid(1024), block 1024; pairs sorted by expert + XCD-chunked.
__global__ __launch_bounds__(1024, 4) void expert_kernel(
    const int* __restrict__ x, const float* __restrict__ exp_emb,
    const ushort* __restrict__ w1t, const float* __restrict__ exp_b1,
    const int* __restrict__ ridx, const int* __restrict__ order,
    float* __restrict__ p_part) {
  const int id     = blockIdx.x;           // 0..1023
  const int xcd    = id & 7;
  const int within = id >> 3;              // 0..127
  const int slot   = xcd * 128 + within;   // contiguous sorted chunk per XCD
  const int pr     = order[slot >> 3];
  const int sblk   = slot & 7;
  const int b      = pr >> 1;
  const int tid    = threadIdx.x;

  __shared__ __align__(16) ushort lB[64 * 1024];   // 128 KiB token tile

  const int e = ridx[pr];

  // gather mapping: thread covers token row (tid>>4), 4 floats at (tid&15)*4
  const int grow = tid >> 4, kq4 = (tid & 15) * 4;
  const int tok  = x[b * S_ + sblk * 64 + grow];
  const float* gptr = exp_emb + ((size_t)e * V_ + tok) * D_ + kq4;
  const int swz  = (grow & 7) << 3;
  const int gdst = grow * 1024 + (((kq4 & ~7) ^ swz) + (kq4 & 7));  // + slab*64

  const int wid = tid >> 6, lane = tid & 63;
  const int l15 = lane & 15, l16 = lane >> 4;
  const int sw  = (l15 & 7) << 3;
  const int kso = wid & 1;                 // per-wave ks-order stagger

  // A fragment stream: frag(kk, i) at aLane + (kk*64 + wid*4 + i)*512
  const ushort* aLane = w1t + (size_t)e * (32 * 64 * 512)
                        + ((size_t)wid * 4) * 512 + (size_t)lane * 8;
  #define LOADA(kk_, i_) \
    (*reinterpret_cast<const bf16x8*>(aLane + ((size_t)((kk_) * 64 + (i_))) * 512))

  f32x4 acc[4][4];
  #pragma unroll
  for (int i = 0; i < 4; ++i)
    #pragma unroll
    for (int j = 0; j < 4; ++j) acc[i][j] = (f32x4){0.f, 0.f, 0.f, 0.f};

  // ---- prologue: slab0 loaded+written; slab1 loads held in stP[1]
  f32x4 stP[2];
  stP[0] = __builtin_nontemporal_load(reinterpret_cast<const f32x4*>(gptr));
  {
    uint2 w;
    w.x = pk2(stP[0][0], stP[0][1]); w.y = pk2(stP[0][2], stP[0][3]);
    *reinterpret_cast<uint2*>(&lB[gdst]) = w;
  }
  stP[1] = __builtin_nontemporal_load(reinterpret_cast<const f32x4*>(gptr + 64));
  __syncthreads();

  // ---- main loop: 16 slabs; at iter s: lB has slabs [0,s], stP[(s+1)&1] = slab s+1
  #pragma unroll
  for (int s = 0; s < 16; ++s) {
    const int cur = s & 1;
    // (a) issue gather for slab s+2 into stP[cur] (parity (s+2)&1 == cur)
    if (s + 2 < 16) {
      stP[cur] = __builtin_nontemporal_load(
          reinterpret_cast<const f32x4*>(gptr + (s + 2) * 64));
    }
    // (b) compute kk = 2s, 2s+1 on slab s (order staggered by wave parity)
    #pragma unroll
    for (int ksi = 0; ksi < 2; ++ksi) {
      const int ks = ksi ^ kso;
      const int kk = s * 2 + ks;
      const int colk = s * 64 + (((ks << 5) | (l16 << 3)) ^ sw);
      bf16x8 bfr[4], af[4];
      #pragma unroll
      for (int j = 0; j < 4; ++j)
        bfr[j] = *reinterpret_cast<const bf16x8*>(&lB[(j * 16 + l15) * 1024 + colk]);
      #pragma unroll
      for (int i = 0; i < 4; ++i) af[i] = LOADA(kk, i);
      __builtin_amdgcn_s_setprio(1);
      #pragma unroll
      for (int i = 0; i < 4; ++i)
        #pragma unroll
        for (int j = 0; j < 4; ++j)
          acc[i][j] = __builtin_amdgcn_mfma_f32_16x16x32_bf16(af[i], bfr[j], acc[i][j], 0, 0, 0);
      __builtin_amdgcn_s_setprio(0);
    }
    // (c) write slab s+1 from stP[cur^1]
    if (s + 1 < 16) {
      uint2 w;
      w.x = pk2(stP[cur ^ 1][0], stP[cur ^ 1][1]);
      w.y = pk2(stP[cur ^ 1][2], stP[cur ^ 1][3]);
      *reinterpret_cast<uint2*>(&lB[gdst + (s + 1) * 64]) = w;
    }
    __syncthreads();
  }
  #undef LOADA

  // ---- epilogue: + bias, ReLU, sum over 64 s columns, store partials
  float* outRow = p_part + (size_t)(sblk * NPAIR + pr) * H_;
  const float* biasE = exp_b1 + e * H_;
  #pragma unroll
  for (int i = 0; i < 4; ++i) {
    #pragma unroll
    for (int r = 0; r < 4; ++r) {
      const int h = wid * 64 + i * 16 + l16 * 4 + r;
      const float bias = biasE[h];
      float v = 0.f;
      #pragma unroll
      for (int j = 0; j < 4; ++j) v += fmaxf(acc[i][j][r] + bias, 0.f);
      #pragma unroll
      for (int m = 1; m < 16; m <<= 1) v += __shfl_xor(v, m);  // reduce 16 s-cols
      if (l15 == 0) outRow[h] = v;
    }
  }
}

// ---------------------------------------------------------------------------
// Kernel 4: out[b][c] = sum_k rw * ( (sum_sb p_part)/S @ W2[e] + b2[e] )
__global__ void finalize_kernel(const float* __restrict__ p_part,
                                const int* __restrict__ ridx, const float* __restrict__ rwgt,
                                const float* __restrict__ w2, const float* __restrict__ b2,
                                float* __restrict__ out) {
  const int b = blockIdx.x, t = threadIdx.x;
  const int c = t & 15, g = t >> 4;
  __shared__ float red[16][17];
  float res = 0.f;
  for (int kk = 0; kk < 2; ++kk) {
    const int pr = b * 2 + kk;
    const int e = ridx[pr];
    const float w = rwgt[pr];
    float dot = 0.f;
    for (int h = g; h < H_; h += 16) {
      float pm = 0.f;
      #pragma unroll
      for (int sb = 0; sb < 8; ++sb) pm += p_part[(size_t)(sb * NPAIR + pr) * H_ + h];
      dot += pm * w2[((size_t)e * H_ + h) * C_ + c];
    }
    red[g][c] = dot;
    __syncthreads();
    if (g == 0) {
      float s = 0.f;
      #pragma unroll
      for (int i = 0; i < 16; ++i) s += red[i][c];
      res += w * (s * (1.f / (float)S_) + b2[e * C_ + c]);
    }
    __syncthreads();
  }
  if (g == 0) out[b * C_ + c] = res;
}

// ---------------------------------------------------------------------------
extern "C" void kernel_launch(void* const* d_in, const int* in_sizes, int n_in,
                              void* d_out, int out_size, void* d_ws, size_t ws_size,
                              hipStream_t stream) {
  const int*   x    = (const int*)  d_in[0];
  const float* emb  = (const float*)d_in[1];
  const float* gw1  = (const float*)d_in[2];
  const float* gb1  = (const float*)d_in[3];
  const float* gw2  = (const float*)d_in[4];
  const float* gb2  = (const float*)d_in[5];
  const float* eemb = (const float*)d_in[6];
  const float* ew1  = (const float*)d_in[7];
  const float* eb1  = (const float*)d_in[8];
  const float* ew2  = (const float*)d_in[9];
  const float* eb2  = (const float*)d_in[10];
  float* out = (float*)d_out;

  char* ws = (char*)d_ws;
  const size_t OFF_W1T   = 0;                            // 16 MiB
  const size_t OFF_PART  = (size_t)16 << 20;             // 2 MiB
  const size_t OFF_RIDX  = OFF_PART + ((size_t)2 << 20);
  const size_t OFF_RWGT  = OFF_RIDX + 1024;
  const size_t OFF_ORDER = OFF_RWGT + 1024;
  const size_t OFF_PPART = OFF_ORDER + 1024;             // 4 MiB

  ushort* w1t    = (ushort*)(ws + OFF_W1T);
  float*  part   = (float*) (ws + OFF_PART);
  int*    ridx   = (int*)   (ws + OFF_RIDX);
  float*  rwgt   = (float*) (ws + OFF_RWGT);
  int*    order  = (int*)   (ws + OFF_ORDER);
  float*  ppart  = (float*) (ws + OFF_PPART);

  prep_kernel<<<dim3(2560), 256, 0, stream>>>(ew1, w1t, x, emb, part);
  gate_kernel<<<dim3(B_), 256, 0, stream>>>(part, gw1, gb1, gw2, gb2, ridx, rwgt);
  sort_pairs_kernel<<<dim3(1), 128, 0, stream>>>(ridx, order);
  expert_kernel<<<dim3(1024), 1024, 0, stream>>>(x, eemb, w1t, eb1, ridx, order, ppart);
  finalize_kernel<<<dim3(B_), 256, 0, stream>>>(ppart, ridx, rwgt, ew2, eb2, out);
}

// Round 18
// 256.600 us; speedup vs baseline: 1.1056x; 1.1056x over previous
//
#include <hip/hip_runtime.h>
#include <hip/hip_bf16.h>

// Problem constants
#define V_   16000
#define D_   1024
#define H_   1024
#define E_   8
#define C_   16
#define B_   64
#define S_   512
#define GH_  256
#define NPAIR 128   // B_ * K(=2)

typedef short  bf16x8 __attribute__((ext_vector_type(8)));
typedef ushort u16x8  __attribute__((ext_vector_type(8)));
typedef float  f32x4  __attribute__((ext_vector_type(4)));

static __device__ __forceinline__ ushort f2bf(float f) {
  union { float f; unsigned u; } un; un.f = f;
  unsigned u = un.u;
  return (ushort)((u + 0x7FFFu + ((u >> 16) & 1u)) >> 16);  // RNE
}

static __device__ __forceinline__ unsigned pk2(float lo, float hi) {
  __hip_bfloat162 h = __float22bfloat162_rn(make_float2(lo, hi));  // v_cvt_pk_bf16_f32
  unsigned r; __builtin_memcpy(&r, &h, sizeof(r)); return r;
}

// ---------------------------------------------------------------------------
// Kernel 0 (fused prep):
//  blocks [0,2048): repack exp_w1 (E,D,H) f32 -> w1t bf16 in MFMA-fragment order:
//   ushort offset = ((e*32 + kk)*64 + f)*512 + lane*8, element j holds
//   A[h = f*16 + (lane&15)][k = kk*32 + (lane>>4)*8 + j]
//  blocks [2048,2560): partial pooling partial[b][sb][d]
__global__ void prep_kernel(const float* __restrict__ w1, ushort* __restrict__ w1t,
                            const int* __restrict__ x, const float* __restrict__ emb,
                            float* __restrict__ partial) {
  __shared__ float tile[64][65];
  const int id = blockIdx.x;
  if (id < 2048) {
    const int e = id >> 8, rem = id & 255;
    const int dtile = rem & 15, htile = rem >> 4;
    const int d0 = dtile * 64, h0 = htile * 64;
    const float* src = w1 + (size_t)e * D_ * H_;
    for (int i = threadIdx.x; i < 64 * 64; i += 256) {
      int r = i >> 6, c = i & 63;                 // r: d-local (k), c: h-local
      tile[r][c] = src[(size_t)(d0 + r) * H_ + h0 + c];
    }
    __syncthreads();
    for (int i = threadIdx.x; i < 512; i += 256) {
      int chunk = i >> 6, lane = i & 63;
      int kkl = chunk >> 2, htl = chunk & 3;
      int l15 = lane & 15, l16 = lane >> 4;
      u16x8 v;
      #pragma unroll
      for (int j = 0; j < 8; ++j)
        v[j] = f2bf(tile[kkl * 32 + l16 * 8 + j][htl * 16 + l15]);
      size_t off = ((size_t)((e * 32 + dtile * 2 + kkl) * 64 + htile * 4 + htl)) * 512 + lane * 8;
      *reinterpret_cast<u16x8*>(w1t + off) = v;
    }
  } else {
    const int pid = id - 2048;
    const int b = pid >> 3, sb = pid & 7, t = threadIdx.x;
    const int* xr = x + b * S_ + sb * 64;
    float4 acc = make_float4(0.f, 0.f, 0.f, 0.f);
    #pragma unroll 4
    for (int s = 0; s < 64; ++s) {
      const float4* row = reinterpret_cast<const float4*>(emb + (size_t)xr[s] * D_);
      float4 v = row[t];
      acc.x += v.x; acc.y += v.y; acc.z += v.z; acc.w += v.w;
    }
    reinterpret_cast<float4*>(partial + ((size_t)b * 8 + sb) * D_)[t] = acc;
  }
}

// ---------------------------------------------------------------------------
// Kernel 1: reduce partials + gating MLP + top-2 + renormalize (all f32)
__global__ void gate_kernel(const float* __restrict__ partial,
                            const float* __restrict__ gw1, const float* __restrict__ gb1,
                            const float* __restrict__ gw2, const float* __restrict__ gb2,
                            int* __restrict__ ridx, float* __restrict__ rwgt) {
  const int b = blockIdx.x, j = threadIdx.x;
  __shared__ float pl[D_];
  __shared__ float hid[GH_];
  __shared__ float logits[E_];
  for (int d = j; d < D_; d += 256) {
    float s = 0.f;
    #pragma unroll
    for (int sb = 0; sb < 8; ++sb) s += partial[((size_t)b * 8 + sb) * D_ + d];
    pl[d] = s * (1.f / (float)S_);
  }
  __syncthreads();
  float acc = gb1[j];
  for (int d = 0; d < D_; ++d) acc += pl[d] * gw1[d * GH_ + j];
  hid[j] = fmaxf(acc, 0.f);
  __syncthreads();
  if (j < E_) {
    float l = gb2[j];
    for (int i = 0; i < GH_; ++i) l += hid[i] * gw2[i * E_ + j];
    logits[j] = l;
  }
  __syncthreads();
  if (j == 0) {
    int i0 = 0; float v0 = logits[0];
    for (int i = 1; i < E_; ++i) if (logits[i] > v0) { v0 = logits[i]; i0 = i; }
    int i1 = -1; float v1 = -3.0e38f;
    for (int i = 0; i < E_; ++i) {
      if (i == i0) continue;
      if (logits[i] > v1) { v1 = logits[i]; i1 = i; }
    }
    float r1 = expf(v1 - v0);
    float norm = 1.f + r1;
    ridx[b * 2 + 0] = i0;         ridx[b * 2 + 1] = i1;
    rwgt[b * 2 + 0] = 1.f / norm; rwgt[b * 2 + 1] = r1 / norm;
  }
}

// ---------------------------------------------------------------------------
// Kernel 2: stable counting-rank sort of pairs by expert id. 1 block, 128 thr.
__global__ void sort_pairs_kernel(const int* __restrict__ ridx, int* __restrict__ order) {
  __shared__ int se[NPAIR];
  const int t = threadIdx.x;
  se[t] = ridx[t];
  __syncthreads();
  const int e = se[t];
  int rank = 0;
  for (int j = 0; j < NPAIR; ++j) {
    const int ej = se[j];
    rank += (ej < e || (ej == e && j < t)) ? 1 : 0;
  }
  order[rank] = t;
}

// ---------------------------------------------------------------------------
// Kernel 3: token-stationary gathered GEMM + bias + ReLU + sum over s.
//   EXACT round-12 kernel (best measured: 256.9 us total). Block owns 64
//   tokens x ALL H=1024, K=1024 (gather-once). Token tile (64x1024 bf16,
//   swizzled) in LDS (128 KiB), each slab written once, gather 2 slabs
//   ahead. 16 waves of 1024 threads: wave tile 64h x 64s (acc[4][4] = 64
//   VGPR -> 4 waves/SIMD). A (w1t) fragment-direct global->VGPR JIT
//   (L2-resident via sort+XCD chunking). 17 barriers.
//   r13-r17 lessons: do NOT change the wave tile, do NOT add reg prefetch
//   (VGPR pressure), do NOT coarsen intervals, do NOT stagger/setprio.
// grid(1024), block 1024; pairs sorted by expert + XCD-chunked.
__global__ __launch_bounds__(1024) void expert_kernel(
    const int* __restrict__ x, const float* __restrict__ exp_emb,
    const ushort* __restrict__ w1t, const float* __restrict__ exp_b1,
    const int* __restrict__ ridx, const int* __restrict__ order,
    float* __restrict__ p_part) {
  const int id     = blockIdx.x;           // 0..1023
  const int xcd    = id & 7;
  const int within = id >> 3;              // 0..127
  const int slot   = xcd * 128 + within;   // contiguous sorted chunk per XCD
  const int pr     = order[slot >> 3];
  const int sblk   = slot & 7;
  const int b      = pr >> 1;
  const int tid    = threadIdx.x;

  __shared__ __align__(16) ushort lB[64 * 1024];   // 128 KiB token tile

  const int e = ridx[pr];

  // gather mapping: thread covers token row (tid>>4), 4 floats at (tid&15)*4
  const int grow = tid >> 4, kq4 = (tid & 15) * 4;
  const int tok  = x[b * S_ + sblk * 64 + grow];
  const float* gptr = exp_emb + ((size_t)e * V_ + tok) * D_ + kq4;
  const int swz  = (grow & 7) << 3;
  const int gdst = grow * 1024 + (((kq4 & ~7) ^ swz) + (kq4 & 7));  // + slab*64

  const int wid = tid >> 6, lane = tid & 63;
  const int l15 = lane & 15, l16 = lane >> 4;
  const int sw  = (l15 & 7) << 3;

  // A fragment stream: frag(kk, i) at aLane + (kk*64 + wid*4 + i)*512
  const ushort* aLane = w1t + (size_t)e * (32 * 64 * 512)
                        + ((size_t)wid * 4) * 512 + (size_t)lane * 8;
  #define LOADA(kk_, i_) \
    (*reinterpret_cast<const bf16x8*>(aLane + ((size_t)((kk_) * 64 + (i_))) * 512))

  f32x4 acc[4][4];
  #pragma unroll
  for (int i = 0; i < 4; ++i)
    #pragma unroll
    for (int j = 0; j < 4; ++j) acc[i][j] = (f32x4){0.f, 0.f, 0.f, 0.f};

  // ---- prologue: slab0 loaded+written; slab1 loads held in stP[1]
  f32x4 stP[2];
  stP[0] = __builtin_nontemporal_load(reinterpret_cast<const f32x4*>(gptr));
  {
    uint2 w;
    w.x = pk2(stP[0][0], stP[0][1]); w.y = pk2(stP[0][2], stP[0][3]);
    *reinterpret_cast<uint2*>(&lB[gdst]) = w;
  }
  stP[1] = __builtin_nontemporal_load(reinterpret_cast<const f32x4*>(gptr + 64));
  __syncthreads();

  // ---- main loop: 16 slabs; at iter s: lB has slabs [0,s], stP[(s+1)&1] = slab s+1
  #pragma unroll
  for (int s = 0; s < 16; ++s) {
    const int cur = s & 1;
    // (a) issue gather for slab s+2 into stP[cur] (parity (s+2)&1 == cur)
    if (s + 2 < 16) {
      stP[cur] = __builtin_nontemporal_load(
          reinterpret_cast<const f32x4*>(gptr + (s + 2) * 64));
    }
    // (b) compute kk = 2s, 2s+1 on slab s
    #pragma unroll
    for (int ks = 0; ks < 2; ++ks) {
      const int kk = s * 2 + ks;
      const int colk = s * 64 + (((ks << 5) | (l16 << 3)) ^ sw);
      bf16x8 bfr[4], af[4];
      #pragma unroll
      for (int j = 0; j < 4; ++j)
        bfr[j] = *reinterpret_cast<const bf16x8*>(&lB[(j * 16 + l15) * 1024 + colk]);
      #pragma unroll
      for (int i = 0; i < 4; ++i) af[i] = LOADA(kk, i);
      #pragma unroll
      for (int i = 0; i < 4; ++i)
        #pragma unroll
        for (int j = 0; j < 4; ++j)
          acc[i][j] = __builtin_amdgcn_mfma_f32_16x16x32_bf16(af[i], bfr[j], acc[i][j], 0, 0, 0);
    }
    // (c) write slab s+1 from stP[cur^1]
    if (s + 1 < 16) {
      uint2 w;
      w.x = pk2(stP[cur ^ 1][0], stP[cur ^ 1][1]);
      w.y = pk2(stP[cur ^ 1][2], stP[cur ^ 1][3]);
      *reinterpret_cast<uint2*>(&lB[gdst + (s + 1) * 64]) = w;
    }
    __syncthreads();
  }
  #undef LOADA

  // ---- epilogue: + bias, ReLU, sum over 64 s columns, store partials
  float* outRow = p_part + (size_t)(sblk * NPAIR + pr) * H_;
  const float* biasE = exp_b1 + e * H_;
  #pragma unroll
  for (int i = 0; i < 4; ++i) {
    #pragma unroll
    for (int r = 0; r < 4; ++r) {
      const int h = wid * 64 + i * 16 + l16 * 4 + r;
      const float bias = biasE[h];
      float v = 0.f;
      #pragma unroll
      for (int j = 0; j < 4; ++j) v += fmaxf(acc[i][j][r] + bias, 0.f);
      #pragma unroll
      for (int m = 1; m < 16; m <<= 1) v += __shfl_xor(v, m);  // reduce 16 s-cols
      if (l15 == 0) outRow[h] = v;
    }
  }
}

// ---------------------------------------------------------------------------
// Kernel 4: out[b][c] = sum_k rw * ( (sum_sb p_part)/S @ W2[e] + b2[e] )
__global__ void finalize_kernel(const float* __restrict__ p_part,
                                const int* __restrict__ ridx, const float* __restrict__ rwgt,
                                const float* __restrict__ w2, const float* __restrict__ b2,
                                float* __restrict__ out) {
  const int b = blockIdx.x, t = threadIdx.x;
  const int c = t & 15, g = t >> 4;
  __shared__ float red[16][17];
  float res = 0.f;
  for (int kk = 0; kk < 2; ++kk) {
    const int pr = b * 2 + kk;
    const int e = ridx[pr];
    const float w = rwgt[pr];
    float dot = 0.f;
    for (int h = g; h < H_; h += 16) {
      float pm = 0.f;
      #pragma unroll
      for (int sb = 0; sb < 8; ++sb) pm += p_part[(size_t)(sb * NPAIR + pr) * H_ + h];
      dot += pm * w2[((size_t)e * H_ + h) * C_ + c];
    }
    red[g][c] = dot;
    __syncthreads();
    if (g == 0) {
      float s = 0.f;
      #pragma unroll
      for (int i = 0; i < 16; ++i) s += red[i][c];
      res += w * (s * (1.f / (float)S_) + b2[e * C_ + c]);
    }
    __syncthreads();
  }
  if (g == 0) out[b * C_ + c] = res;
}

// ---------------------------------------------------------------------------
extern "C" void kernel_launch(void* const* d_in, const int* in_sizes, int n_in,
                              void* d_out, int out_size, void* d_ws, size_t ws_size,
                              hipStream_t stream) {
  const int*   x    = (const int*)  d_in[0];
  const float* emb  = (const float*)d_in[1];
  const float* gw1  = (const float*)d_in[2];
  const float* gb1  = (const float*)d_in[3];
  const float* gw2  = (const float*)d_in[4];
  const float* gb2  = (const float*)d_in[5];
  const float* eemb = (const float*)d_in[6];
  const float* ew1  = (const float*)d_in[7];
  const float* eb1  = (const float*)d_in[8];
  const float* ew2  = (const float*)d_in[9];
  const float* eb2  = (const float*)d_in[10];
  float* out = (float*)d_out;

  char* ws = (char*)d_ws;
  const size_t OFF_W1T   = 0;                            // 16 MiB
  const size_t OFF_PART  = (size_t)16 << 20;             // 2 MiB
  const size_t OFF_RIDX  = OFF_PART + ((size_t)2 << 20);
  const size_t OFF_RWGT  = OFF_RIDX + 1024;
  const size_t OFF_ORDER = OFF_RWGT + 1024;
  const size_t OFF_PPART = OFF_ORDER + 1024;             // 4 MiB

  ushort* w1t    = (ushort*)(ws + OFF_W1T);
  float*  part   = (float*) (ws + OFF_PART);
  int*    ridx   = (int*)   (ws + OFF_RIDX);
  float*  rwgt   = (float*) (ws + OFF_RWGT);
  int*    order  = (int*)   (ws + OFF_ORDER);
  float*  ppart  = (float*) (ws + OFF_PPART);

  prep_kernel<<<dim3(2560), 256, 0, stream>>>(ew1, w1t, x, emb, part);
  gate_kernel<<<dim3(B_), 256, 0, stream>>>(part, gw1, gb1, gw2, gb2, ridx, rwgt);
  sort_pairs_kernel<<<dim3(1), 128, 0, stream>>>(ridx, order);
  expert_kernel<<<dim3(1024), 1024, 0, stream>>>(x, eemb, w1t, eb1, ridx, order, ppart);
  finalize_kernel<<<dim3(B_), 256, 0, stream>>>(ppart, ridx, rwgt, ew2, eb2, out);
}